// Round 5
// baseline (392.499 us; speedup 1.0000x reference)
//
#include <hip/hip_runtime.h>
#include <math.h>

#define LSEQ 4096
#define NFFT 8192
#define NF   512     // kept frequency bins
#define NF2  1024    // 2*NF (cos/sin interleaved)
#define NH   768
#define NBH  6144    // 8*768
#define MROWS 6912   // NBH + NH (x rows + k rows share stage-A GEMM)
#define SPLIT_ROW 3456   // partial-1 row split (27*128: block-uniform)

typedef __attribute__((ext_vector_type(8))) short short8;   // 8 bf16 (4 VGPRs)
typedef __attribute__((ext_vector_type(4))) float floatx4;  // MFMA accumulator

__device__ __forceinline__ unsigned short f2bf(float f) {
    unsigned int u = __float_as_uint(f);
    u += 0x7fff + ((u >> 16) & 1);       // round-to-nearest-even
    return (unsigned short)(u >> 16);
}

// 8 f32 (two uint4) -> 8 bf16 packed into one uint4 (RNE, matches f2bf)
__device__ __forceinline__ uint4 cvt8(uint4 lo, uint4 hi) {
    uint4 r;
    r.x = (unsigned)f2bf(__uint_as_float(lo.x)) | ((unsigned)f2bf(__uint_as_float(lo.y)) << 16);
    r.y = (unsigned)f2bf(__uint_as_float(lo.z)) | ((unsigned)f2bf(__uint_as_float(lo.w)) << 16);
    r.z = (unsigned)f2bf(__uint_as_float(hi.x)) | ((unsigned)f2bf(__uint_as_float(hi.y)) << 16);
    r.w = (unsigned)f2bf(__uint_as_float(hi.z)) | ((unsigned)f2bf(__uint_as_float(hi.w)) << 16);
    return r;
}

// -------- fused trig tables: T1[f2][n] and T2[n][f2], bf16 -----------------
__global__ void build_tables(unsigned short* __restrict__ T1,
                             unsigned short* __restrict__ T2) {
    __shared__ unsigned short tile[64][66];   // pad 66: transpose-read conflict-free
    const int t = threadIdx.x;
    const int F0 = blockIdx.x * 64;
    const int N0 = blockIdx.y * 64;
#pragma unroll
    for (int i = 0; i < 16; ++i) {
        int r = (t >> 6) + i * 4;
        int c = t & 63;
        int f2 = F0 + r, n = N0 + c;
        int f = f2 >> 1;
        int p = (f * n) & (NFFT - 1);
        float th = (float)p * (float)(2.0 * M_PI / (double)NFFT);
        float s, cc;
        sincosf(th, &s, &cc);
        unsigned short v = f2bf((f2 & 1) ? s : cc);
        T1[(size_t)f2 * LSEQ + n] = v;
        tile[r][c] = v;
    }
    __syncthreads();
#pragma unroll
    for (int i = 0; i < 16; ++i) {
        int r = (t >> 6) + i * 4;
        int c = t & 63;
        T2[(size_t)(N0 + r) * NF2 + F0 + c] = tile[c][r];
    }
}

// shared MFMA inner phase (both GEMMs): 4x4 16x16x32 fragments per wave
#define COMPUTE(buf)                                                          \
    {                                                                         \
        short8 af[4], bfv[4];                                                 \
        _Pragma("unroll")                                                     \
        for (int i = 0; i < 4; ++i)                                           \
            af[i] = *(const short8*)(As[buf] + (wm + 16 * i + lr) * 32 + lq * 8); \
        _Pragma("unroll")                                                     \
        for (int j = 0; j < 4; ++j)                                           \
            bfv[j] = *(const short8*)(Bs[buf] + (wn + 16 * j + lr) * 32 + lq * 8); \
        _Pragma("unroll")                                                     \
        for (int i = 0; i < 4; ++i)                                           \
            _Pragma("unroll")                                                 \
            for (int j = 0; j < 4; ++j)                                       \
                acc[i][j] = __builtin_amdgcn_mfma_f32_16x16x32_bf16(          \
                    af[i], bfv[j], acc[i][j], 0, 0, 0);                       \
    }

// ======== Stage A: [x;k](fp32, converted in staging) x T1^T -> spectra =====
// R4 counters: FETCH fix (XCD swizzle) confirmed (228->74.5MB) but dur only
// -6% -> stage A is latency/issue-bound, not traffic-bound.  R5 attacks the
// ~160us of non-GEMM time instead: tobf16 (170MB, ~34us) is eliminated by
// reading x/k fp32 directly in the staging loads and converting f32->bf16
// (bit-identical f2bf) in registers before ds_write.  Extra fetch (~57MB)
// hides under the latency-bound schedule; conversion VALU ~7us total.
#define LOADSET_A(s, off)                                      \
    s##a0lo = *(const uint4*)(pa0 + (off));                    \
    s##a0hi = *(const uint4*)(pa0 + (off) + 4);                \
    s##a1lo = *(const uint4*)(pa1 + (off));                    \
    s##a1hi = *(const uint4*)(pa1 + (off) + 4);                \
    s##b0 = *(const uint4*)(pb0 + (off));                      \
    s##b1 = *(const uint4*)(pb1 + (off));

#define WRITESET_A(buf, s)                                     \
    *(uint4*)(As[buf] + q0 * 8) = cvt8(s##a0lo, s##a0hi);      \
    *(uint4*)(As[buf] + q1 * 8) = cvt8(s##a1lo, s##a1hi);      \
    *(uint4*)(Bs[buf] + q0 * 8) = s##b0;                       \
    *(uint4*)(Bs[buf] + q1 * 8) = s##b1;

__global__ __launch_bounds__(256) void gemm_a(
    const float* __restrict__ x,            // [6144,4096] fp32
    const float* __restrict__ kk,           // [768,4096] fp32
    const unsigned short* __restrict__ B,   // T1 [1024,4096] bf16
    float* __restrict__ C,                  // z==0 target [6912,1024]
    float* __restrict__ P1a,                // z==1, rows < SPLIT_ROW
    float* __restrict__ P1b,                // z==1, rows >= SPLIT_ROW
    int gx, int gy, int N, int ldk, int Ksub)
{
    __shared__ __align__(16) unsigned short As[2][128 * 32];
    __shared__ __align__(16) unsigned short Bs[2][128 * 32];
    const int t = threadIdx.x;
    const int w = t >> 6, l = t & 63;

    // chunked bijective XCD swizzle (nwg = 864, %8==0)
    const int nwg = gridDim.x;
    const int bid = blockIdx.x;
    const int swz = (bid & 7) * (nwg >> 3) + (bid >> 3);
    const int bx = swz % gx;
    const int rem = swz / gx;
    const int by = rem % gy;
    const int bz = rem / gy;

    const int m0 = by * 128, n0 = bx * 128;
    const int wm = (w >> 1) * 64, wn = (w & 1) * 64;
    const int lq = l >> 4, lr = l & 15;
    const int kbase = bz * Ksub;

    floatx4 acc[4][4];
#pragma unroll
    for (int i = 0; i < 4; ++i)
#pragma unroll
        for (int j = 0; j < 4; ++j)
            acc[i][j] = (floatx4){0.f, 0.f, 0.f, 0.f};

    // staging: per thread 2 A-chunks (8 f32 each) + 2 B-chunks (8 bf16 each)
    const int q0 = t, q1 = t + 256;
    const int r0 = q0 >> 2, e0 = (q0 & 3) * 8;
    const int r1 = q1 >> 2, e1 = (q1 & 3) * 8;
    const int row0 = m0 + r0, row1 = m0 + r1;
    const float* base0 = (row0 < NBH) ? (x + (size_t)row0 * ldk)
                                      : (kk + (size_t)(row0 - NBH) * ldk);
    const float* base1 = (row1 < NBH) ? (x + (size_t)row1 * ldk)
                                      : (kk + (size_t)(row1 - NBH) * ldk);
    const float* pa0 = base0 + e0 + kbase;
    const float* pa1 = base1 + e1 + kbase;
    const unsigned short* pb0 = B + (size_t)(n0 + r0) * ldk + e0 + kbase;
    const unsigned short* pb1 = B + (size_t)(n0 + r1) * ldk + e1 + kbase;

    uint4 Xa0lo, Xa0hi, Xa1lo, Xa1hi, Xb0, Xb1;   // reg set X (even tiles)
    uint4 Ya0lo, Ya0hi, Ya1lo, Ya1hi, Yb0, Yb1;   // reg set Y (odd tiles)

    // prologue: tile0 -> X -> buf0; tile1 -> Y (in flight)
    LOADSET_A(X, 0)
    WRITESET_A(0, X)
    LOADSET_A(Y, 32)
    __syncthreads();

    const int T = Ksub >> 5;   // 64 K-tiles
    for (int tt = 0; tt + 4 <= T; tt += 2) {
        LOADSET_A(X, (tt + 2) * 32)
        COMPUTE(0)
        WRITESET_A(1, Y)   // vmcnt wait: Y loads, 1 full iter old
        __syncthreads();
        LOADSET_A(Y, (tt + 3) * 32)
        COMPUTE(1)
        WRITESET_A(0, X)
        __syncthreads();
    }
    COMPUTE(0)
    WRITESET_A(1, Y)
    __syncthreads();
    COMPUTE(1)

    // epilogue target: z=0 -> C; z=1 -> partial (block-uniform row split)
    float* Cb;
    if (bz == 0) {
        Cb = C;
    } else {
        Cb = (m0 < SPLIT_ROW) ? P1a : (P1b - (size_t)SPLIT_ROW * N);
    }
    // C/D layout: col = lane&15, row = (lane>>4)*4 + reg  [verified m89/m91]
#pragma unroll
    for (int i = 0; i < 4; ++i)
#pragma unroll
        for (int j = 0; j < 4; ++j)
#pragma unroll
            for (int r = 0; r < 4; ++r) {
                int row = m0 + wm + 16 * i + lq * 4 + r;
                int col = n0 + wn + 16 * j + lr;
                Cb[(size_t)row * N + col] = acc[i][j][r];
            }
}

// ======== Stage B: AB(bf16) x T2^T -> y (fp32) =============================
#define LOADSET_B(s, off)                                      \
    s##a0 = *(const uint4*)(pa0 + (off));                      \
    s##a1 = *(const uint4*)(pa1 + (off));                      \
    s##b0 = *(const uint4*)(pb0 + (off));                      \
    s##b1 = *(const uint4*)(pb1 + (off));

#define WRITESET_B(buf, s)                                     \
    *(uint4*)(As[buf] + q0 * 8) = s##a0;                       \
    *(uint4*)(As[buf] + q1 * 8) = s##a1;                       \
    *(uint4*)(Bs[buf] + q0 * 8) = s##b0;                       \
    *(uint4*)(Bs[buf] + q1 * 8) = s##b1;

__global__ __launch_bounds__(256) void gemm_b(
    const unsigned short* __restrict__ A,   // [M,ldk] bf16
    const unsigned short* __restrict__ B,   // [N,ldk] bf16
    float* __restrict__ C,                  // [M,N] fp32
    int gx, int gy, int N, int ldk, int K)
{
    __shared__ __align__(16) unsigned short As[2][128 * 32];
    __shared__ __align__(16) unsigned short Bs[2][128 * 32];
    const int t = threadIdx.x;
    const int w = t >> 6, l = t & 63;

    // chunked bijective XCD swizzle (nwg = 1536, %8==0)
    const int nwg = gridDim.x;
    const int bid = blockIdx.x;
    const int swz = (bid & 7) * (nwg >> 3) + (bid >> 3);
    const int bx = swz % gx;
    const int by = swz / gx;

    const int m0 = by * 128, n0 = bx * 128;
    const int wm = (w >> 1) * 64, wn = (w & 1) * 64;
    const int lq = l >> 4, lr = l & 15;

    floatx4 acc[4][4];
#pragma unroll
    for (int i = 0; i < 4; ++i)
#pragma unroll
        for (int j = 0; j < 4; ++j)
            acc[i][j] = (floatx4){0.f, 0.f, 0.f, 0.f};

    const int q0 = t, q1 = t + 256;
    const int r0 = q0 >> 2, e0 = (q0 & 3) * 8;
    const int r1 = q1 >> 2, e1 = (q1 & 3) * 8;
    const unsigned short* pa0 = A + (size_t)(m0 + r0) * ldk + e0;
    const unsigned short* pa1 = A + (size_t)(m0 + r1) * ldk + e1;
    const unsigned short* pb0 = B + (size_t)(n0 + r0) * ldk + e0;
    const unsigned short* pb1 = B + (size_t)(n0 + r1) * ldk + e1;

    uint4 Xa0, Xa1, Xb0, Xb1;
    uint4 Ya0, Ya1, Yb0, Yb1;

    LOADSET_B(X, 0)
    WRITESET_B(0, X)
    LOADSET_B(Y, 32)
    __syncthreads();

    const int T = K >> 5;   // 32 K-tiles
    for (int tt = 0; tt + 4 <= T; tt += 2) {
        LOADSET_B(X, (tt + 2) * 32)
        COMPUTE(0)
        WRITESET_B(1, Y)
        __syncthreads();
        LOADSET_B(Y, (tt + 3) * 32)
        COMPUTE(1)
        WRITESET_B(0, X)
        __syncthreads();
    }
    COMPUTE(0)
    WRITESET_B(1, Y)
    __syncthreads();
    COMPUTE(1)

#pragma unroll
    for (int i = 0; i < 4; ++i)
#pragma unroll
        for (int j = 0; j < 4; ++j)
#pragma unroll
            for (int r = 0; r < 4; ++r) {
                int row = m0 + wm + 16 * i + lq * 4 + r;
                int col = n0 + wn + 16 * j + lr;
                C[(size_t)row * N + col] = acc[i][j][r];
            }
}

// -------- combine: sum K-split partials + complex multiply + scaling -------
__global__ void combine(const float* __restrict__ C1,
                        const float* __restrict__ P1a,
                        const float* __restrict__ P1b,
                        unsigned short* __restrict__ AB) {
    int idx = blockIdx.x * blockDim.x + threadIdx.x;   // bh*512 + f
    int bh = idx >> 9;
    int f = idx & (NF - 1);
    int h = bh % NH;
    const float* xc = C1 + (size_t)bh * NF2 + 2 * f;
    const float* xp = (bh < SPLIT_ROW)
        ? (P1a + (size_t)bh * NF2 + 2 * f)
        : (P1b + (size_t)(bh - SPLIT_ROW) * NF2 + 2 * f);
    const int kr = NBH + h;    // always >= SPLIT_ROW
    const float* kc = C1 + (size_t)kr * NF2 + 2 * f;
    const float* kp = P1b + (size_t)(kr - SPLIT_ROW) * NF2 + 2 * f;
    float Xre = xc[0] + xp[0], Xim = -(xc[1] + xp[1]);
    float Kre = kc[0] + kp[0], Kim = -(kc[1] + kp[1]);
    float s = (f == 0 ? 1.0f : 2.0f) * (1.0f / (float)NFFT);
    float Av = s * (Xre * Kre - Xim * Kim);
    float Bv = -(s * (Xre * Kim + Xim * Kre));
    unsigned int packed = (unsigned int)f2bf(Av) | ((unsigned int)f2bf(Bv) << 16);
    *(unsigned int*)(AB + (size_t)bh * NF2 + 2 * f) = packed;
}

extern "C" void kernel_launch(void* const* d_in, const int* in_sizes, int n_in,
                              void* d_out, int out_size, void* d_ws, size_t ws_size,
                              hipStream_t stream) {
    const float* x = (const float*)d_in[0];   // [8,768,4096]
    const float* k = (const float*)d_in[1];   // [768,4096]
    float* y = (float*)d_out;

    // ws layout (43.5 MB of 45.1 MB proven):
    unsigned short* T1 = (unsigned short*)d_ws;                 // [1024,4096] bf16,  8.39 MB
    unsigned short* T2 = T1 + (size_t)NF2 * LSEQ;               // [4096,1024] bf16,  8.39 MB
    unsigned short* AB = T2 + (size_t)LSEQ * NF2;               // [6144,1024] bf16, 12.58 MB
    float* P1a = (float*)(AB + (size_t)NBH * NF2);              // [3456,1024] f32,  14.16 MB

    // d_out as scratch until stage B overwrites (Abm eliminated):
    float* C1 = (float*)d_out;                                  // [6912,1024] f32, 28.31 MB
    float* P1b = C1 + (size_t)MROWS * NF2;                      // [3456,1024] f32, 14.16 MB

    const int blk = 256;
    hipLaunchKernelGGL(build_tables, dim3(NF2 / 64, LSEQ / 64), dim3(blk), 0, stream, T1, T2);
    // Stage A: [x;k] fp32 x T1^T, split-K x2, fused f32->bf16 staging
    hipLaunchKernelGGL(gemm_a, dim3(8 * 54 * 2), dim3(blk), 0, stream,
                       x, k, T1, C1, P1a, P1b, 8, 54, NF2, LSEQ, LSEQ / 2);
    hipLaunchKernelGGL(combine, dim3((NBH * NF) / blk), dim3(blk), 0, stream, C1, P1a, P1b, AB);
    // Stage B: [6144,1024] x [1024,4096] -> y
    hipLaunchKernelGGL(gemm_b, dim3(32 * 48), dim3(blk), 0, stream,
                       AB, T2, y, 32, 48, LSEQ, NF2, NF2);
}

// Round 7
// 331.520 us; speedup vs baseline: 1.1839x; 1.1839x over previous
//
#include <hip/hip_runtime.h>
#include <math.h>

#define LSEQ 4096
#define NFFT 8192
#define NF   512     // kept frequency bins
#define NF2  1024    // 2*NF (cos/sin interleaved)
#define NH   768
#define NBH  6144    // 8*768
#define MROWS 6912   // NBH + NH (x rows + k rows share stage-A GEMM)
#define SPLIT_ROW 3584   // partial-1 row split (14*256: block-uniform at BM=256)

typedef __attribute__((ext_vector_type(8))) short short8;   // 8 bf16 (4 VGPRs)
typedef __attribute__((ext_vector_type(4))) float floatx4;  // MFMA accumulator

__device__ __forceinline__ unsigned short f2bf(float f) {
    unsigned int u = __float_as_uint(f);
    u += 0x7fff + ((u >> 16) & 1);       // round-to-nearest-even
    return (unsigned short)(u >> 16);
}

// direct HBM->LDS async copy, 16B/lane.  LDS dest = wave-uniform base + lane*16.
__device__ __forceinline__ void gld16(const unsigned short* g, const unsigned short* l) {
    __builtin_amdgcn_global_load_lds(
        (const __attribute__((address_space(1))) void*)g,
        (__attribute__((address_space(3))) void*)l, 16, 0, 0);
}

// -------- fused trig tables: T1[f2][n] and T2[n][f2], bf16 -----------------
__global__ void build_tables(unsigned short* __restrict__ T1,
                             unsigned short* __restrict__ T2) {
    __shared__ unsigned short tile[64][66];
    const int t = threadIdx.x;
    const int F0 = blockIdx.x * 64;
    const int N0 = blockIdx.y * 64;
#pragma unroll
    for (int i = 0; i < 16; ++i) {
        int r = (t >> 6) + i * 4;
        int c = t & 63;
        int f2 = F0 + r, n = N0 + c;
        int f = f2 >> 1;
        int p = (f * n) & (NFFT - 1);
        float th = (float)p * (float)(2.0 * M_PI / (double)NFFT);
        float s, cc;
        sincosf(th, &s, &cc);
        unsigned short v = f2bf((f2 & 1) ? s : cc);
        T1[(size_t)f2 * LSEQ + n] = v;
        tile[r][c] = v;
    }
    __syncthreads();
#pragma unroll
    for (int i = 0; i < 16; ++i) {
        int r = (t >> 6) + i * 4;
        int c = t & 63;
        T2[(size_t)(N0 + r) * NF2 + F0 + c] = tile[c][r];
    }
}

// -------- fp32 -> bf16 pack of [x ; k] into one [6912, 4096] matrix --------
__global__ void tobf16(const float* __restrict__ x, const float* __restrict__ kk,
                       unsigned short* __restrict__ o) {
    size_t e = ((size_t)blockIdx.x * 256 + threadIdx.x) * 4;
    const size_t XN = (size_t)NBH * LSEQ;
    const float* s = (e < XN) ? (x + e) : (kk + (e - XN));
    float4 v = *(const float4*)s;
    unsigned int lo = (unsigned int)f2bf(v.x) | ((unsigned int)f2bf(v.y) << 16);
    unsigned int hi = (unsigned int)f2bf(v.z) | ((unsigned int)f2bf(v.w) << 16);
    *(uint2*)(o + e) = make_uint2(lo, hi);
}

// ======== 256x256 8-phase GEMM (T2+T3+T4+T5): C = A[M,K] x B^T[N,K] ========
// R1-R5: the 2-barrier/K-step structure plateaued at ~570-630 TF = its
// measured ceiling (m233).  This is the m201 schedule in plain HIP:
//  - BK=64, 2 LDS bufs (64KB each: A 256x64 + B 256x64 bf16), 512thr/8 waves
//    (2Mx4N), per-wave output 128x64 = 8x4 16x16x32 frags.
//  - 4 phases per K-tile: {stage 1 half-tile (2x gld16) | ds_read subtile |
//    barrier | 16 MFMA (setprio 1) | barrier}.  Counted vmcnt(2) ONCE per
//    K-tile (phase 0); never drains to 0 in-loop.  Ledger: entering phase 0
//    of iter kt, outstanding = tile kt's 8 calls (issued iter kt-1) + 2 just
//    issued for tile kt+1 -> vmcnt(2) proves tile kt landed; barrier
//    publishes it to all waves.  Stage target buf (kt+1)&1 was fully
//    consumed in iter kt-1 -> no clobber race.
//  - st_16x32 LDS swizzle (m201: slot ^= ((row>>2)&1)<<1, bank-conflict
//    141x) applied BOTH sides (rule #21): linear gld16 dest + inverse-
//    swizzled per-lane GLOBAL col + swizzled ds_read col.
__global__ __launch_bounds__(512) void gemm8(
    const unsigned short* __restrict__ A,   // [M,ldk] bf16
    const unsigned short* __restrict__ B,   // [N,ldk] bf16 (transposed operand)
    float* __restrict__ C,                  // z==0 target [M,N] fp32
    float* __restrict__ P1a,                // z==1 target, rows < SPLIT_ROW
    float* __restrict__ P1b,                // z==1 target, rows >= SPLIT_ROW
    int gx, int gy, int N, int ldk, int Ksub)
{
    __shared__ __align__(16) unsigned short S[2 * 32768];   // 128 KiB: [buf][A|B]
    const int t = threadIdx.x;
    const int wid = t >> 6, l = t & 63;

    // chunked bijective XCD swizzle (nwg = 216 / 384, both %8==0)
    const int nwg = gridDim.x, bid = blockIdx.x;
    const int swz = (bid & 7) * (nwg >> 3) + (bid >> 3);
    const int bx = swz % gx;
    const int rem = swz / gx;
    const int by = rem % gy;
    const int bz = rem / gy;

    const int m0 = by * 256, n0 = bx * 256;
    const int wr = wid >> 2, wc = wid & 3;   // wave tile: rows wr*128, cols wc*64
    const int lq = l >> 4, lr = l & 15;
    const int kbase = bz * Ksub;
    const int NT = Ksub >> 6;                // K-tiles of 64

    // read side: element (row, slot g) lives at LDS slot g ^ ((row>>2&1)<<1);
    // (row>>2)&1 == (lr>>2)&1 for all frag rows (wr*128,wc*64,16i are mult-8/4)
    const int sx = ((lr >> 2) & 1) << 1;
    const int s0 = lq ^ sx;                       // ks=0 slot; ks=1 slot = s0+4
    const int aoff = (wr * 128 + lr) * 64 + s0 * 8;
    const int boff = 16384 + (wc * 64 + lr) * 64 + s0 * 8;

    // stage side: linear LDS dest; lane l covers (row = +wid*8 + (l>>3),
    // lds slot = l&7); its global col-slot = (l&7) ^ (((l>>5)&1)<<1)
    // (since (row>>2)&1 == (l>>5)&1 for all staged rows).
    const int gsl = (l & 7) ^ (((l >> 5) & 1) << 1);
    const unsigned short* pAs = A + (size_t)(m0 + wid * 8 + (l >> 3)) * ldk + kbase + gsl * 8;
    const unsigned short* pBs = B + (size_t)(n0 + wid * 8 + (l >> 3)) * ldk + kbase + gsl * 8;

    floatx4 acc[8][4];
#pragma unroll
    for (int i = 0; i < 8; ++i)
#pragma unroll
        for (int j = 0; j < 4; ++j)
            acc[i][j] = (floatx4){0.f, 0.f, 0.f, 0.f};

// one half-tile (128 rows) = 2 calls of 64 rows (512thr x 16B = 8KB each)
#define STG_A(b, h, kt_)                                                                  \
    gld16(pAs + (size_t)((h)*128     ) * ldk + (kt_) * 64, S + (b)*32768 +         ((h)*128      + wid*8) * 64); \
    gld16(pAs + (size_t)((h)*128 + 64) * ldk + (kt_) * 64, S + (b)*32768 +         ((h)*128 + 64 + wid*8) * 64);
#define STG_B(b, h, kt_)                                                                  \
    gld16(pBs + (size_t)((h)*128     ) * ldk + (kt_) * 64, S + (b)*32768 + 16384 + ((h)*128      + wid*8) * 64); \
    gld16(pBs + (size_t)((h)*128 + 64) * ldk + (kt_) * 64, S + (b)*32768 + 16384 + ((h)*128 + 64 + wid*8) * 64);

#define RD_A(Sc, ip)                                                           \
    _Pragma("unroll") for (int ii = 0; ii < 2; ++ii)                           \
    _Pragma("unroll") for (int ks = 0; ks < 2; ++ks)                           \
        aq[ii][ks] = *(const short8*)((Sc) + aoff + 1024 * ((ip) + ii) + 32 * ks);
#define RD_B(Sc)                                                               \
    _Pragma("unroll") for (int j = 0; j < 4; ++j)                              \
    _Pragma("unroll") for (int ks = 0; ks < 2; ++ks)                           \
        bq[j][ks] = *(const short8*)((Sc) + boff + 1024 * j + 32 * ks);
#define MM(ip)                                                                 \
    __builtin_amdgcn_s_setprio(1);                                             \
    _Pragma("unroll") for (int ii = 0; ii < 2; ++ii)                           \
    _Pragma("unroll") for (int j = 0; j < 4; ++j)                              \
    _Pragma("unroll") for (int ks = 0; ks < 2; ++ks)                           \
        acc[(ip) + ii][j] = __builtin_amdgcn_mfma_f32_16x16x32_bf16(           \
            aq[ii][ks], bq[j][ks], acc[(ip) + ii][j], 0, 0, 0);                \
    __builtin_amdgcn_s_setprio(0);

    // prologue: tile 0 -> buf 0 (8 calls), full drain once
    STG_A(0, 0, 0) STG_A(0, 1, 0) STG_B(0, 0, 0) STG_B(0, 1, 0)
    asm volatile("s_waitcnt vmcnt(0)" ::: "memory");
    __builtin_amdgcn_s_barrier();

    short8 aq[2][2], bq[4][2];

    for (int kt = 0; kt < NT; ++kt) {
        const unsigned short* Sc = S + (size_t)(kt & 1) * 32768;
        const int bs = (kt & 1) ^ 1;
        const bool pf = (kt + 1 < NT);
        // phase 0: stage A-h0(kt+1); counted wait proves tile kt landed
        if (pf) { STG_A(bs, 0, kt + 1) }
        if (pf) asm volatile("s_waitcnt vmcnt(2)" ::: "memory");
        else    asm volatile("s_waitcnt vmcnt(0)" ::: "memory");
        __builtin_amdgcn_s_barrier();
        RD_B(Sc) RD_A(Sc, 0)
        MM(0)
        __builtin_amdgcn_s_barrier();
        // phase 1: stage A-h1(kt+1)
        if (pf) { STG_A(bs, 1, kt + 1) }
        RD_A(Sc, 2)
        __builtin_amdgcn_s_barrier();
        MM(2)
        __builtin_amdgcn_s_barrier();
        // phase 2: stage B-h0(kt+1)
        if (pf) { STG_B(bs, 0, kt + 1) }
        RD_A(Sc, 4)
        __builtin_amdgcn_s_barrier();
        MM(4)
        __builtin_amdgcn_s_barrier();
        // phase 3: stage B-h1(kt+1)
        if (pf) { STG_B(bs, 1, kt + 1) }
        RD_A(Sc, 6)
        __builtin_amdgcn_s_barrier();
        MM(6)
        __builtin_amdgcn_s_barrier();
    }

    // epilogue target: z=0 -> C; z=1 -> partial (block-uniform row split)
    float* Cb;
    if (bz == 0) Cb = C;
    else Cb = (m0 < SPLIT_ROW) ? P1a : (P1b - (size_t)SPLIT_ROW * N);
    // C/D layout: col = lane&15, row = (lane>>4)*4 + reg  [verified m89/m91]
#pragma unroll
    for (int i = 0; i < 8; ++i)
#pragma unroll
        for (int j = 0; j < 4; ++j)
#pragma unroll
            for (int r = 0; r < 4; ++r) {
                int row = m0 + wr * 128 + 16 * i + lq * 4 + r;
                int col = n0 + wc * 64 + 16 * j + lr;
                Cb[(size_t)row * N + col] = acc[i][j][r];
            }
}

// -------- combine: sum K-split partials + complex multiply + scaling -------
__global__ void combine(const float* __restrict__ C1,
                        const float* __restrict__ P1a,
                        const float* __restrict__ P1b,
                        unsigned short* __restrict__ AB) {
    int idx = blockIdx.x * blockDim.x + threadIdx.x;   // bh*512 + f
    int bh = idx >> 9;
    int f = idx & (NF - 1);
    int h = bh % NH;
    const float* xc = C1 + (size_t)bh * NF2 + 2 * f;
    const float* xp = (bh < SPLIT_ROW)
        ? (P1a + (size_t)bh * NF2 + 2 * f)
        : (P1b + (size_t)(bh - SPLIT_ROW) * NF2 + 2 * f);
    const int kr = NBH + h;    // always >= SPLIT_ROW
    const float* kc = C1 + (size_t)kr * NF2 + 2 * f;
    const float* kp = P1b + (size_t)(kr - SPLIT_ROW) * NF2 + 2 * f;
    float Xre = xc[0] + xp[0], Xim = -(xc[1] + xp[1]);
    float Kre = kc[0] + kp[0], Kim = -(kc[1] + kp[1]);
    float s = (f == 0 ? 1.0f : 2.0f) * (1.0f / (float)NFFT);
    float Av = s * (Xre * Kre - Xim * Kim);
    float Bv = -(s * (Xre * Kim + Xim * Kre));
    unsigned int packed = (unsigned int)f2bf(Av) | ((unsigned int)f2bf(Bv) << 16);
    *(unsigned int*)(AB + (size_t)bh * NF2 + 2 * f) = packed;
}

extern "C" void kernel_launch(void* const* d_in, const int* in_sizes, int n_in,
                              void* d_out, int out_size, void* d_ws, size_t ws_size,
                              hipStream_t stream) {
    const float* x = (const float*)d_in[0];   // [8,768,4096]
    const float* k = (const float*)d_in[1];   // [768,4096]
    float* y = (float*)d_out;

    // ws layout (44.0 MB of 45.1 MB proven):
    unsigned short* T1 = (unsigned short*)d_ws;                 // [1024,4096] bf16,  8.39 MB
    unsigned short* T2 = T1 + (size_t)NF2 * LSEQ;               // [4096,1024] bf16,  8.39 MB
    unsigned short* AB = T2 + (size_t)LSEQ * NF2;               // [6144,1024] bf16, 12.58 MB
    float* P1a = (float*)(AB + (size_t)NBH * NF2);              // [3584,1024] f32,  14.68 MB

    // d_out as scratch (98.6 MB of 100.66) until stage B overwrites:
    unsigned short* Abm = (unsigned short*)d_out;               // [6912,4096] bf16, 56.62 MB
    float* C1 = (float*)((char*)d_out + (size_t)MROWS * LSEQ * 2); // [6912,1024] f32, 28.31 MB
    float* P1b = C1 + (size_t)MROWS * NF2;                      // [3328,1024] f32,  13.63 MB

    const int blk = 256;
    hipLaunchKernelGGL(build_tables, dim3(NF2 / 64, LSEQ / 64), dim3(blk), 0, stream, T1, T2);
    hipLaunchKernelGGL(tobf16, dim3((MROWS * LSEQ / 4) / blk), dim3(blk), 0, stream, x, k, Abm);
    // Stage A: [6912,4096] x [4096,1024], 256^2 tiles, split-K x2: 4*27*2=216 WGs
    hipLaunchKernelGGL(gemm8, dim3(4 * 27 * 2), dim3(512), 0, stream,
                       Abm, T1, C1, P1a, P1b, 4, 27, NF2, LSEQ, LSEQ / 2);
    hipLaunchKernelGGL(combine, dim3((NBH * NF) / blk), dim3(blk), 0, stream, C1, P1a, P1b, AB);
    // Stage B: [6144,1024] x [1024,4096] -> y: 16*24=384 WGs
    hipLaunchKernelGGL(gemm8, dim3(16 * 24), dim3(512), 0, stream,
                       AB, T2, y, (float*)nullptr, (float*)nullptr, 16, 24, LSEQ, NF2, NF2);
}

// Round 8
// 309.747 us; speedup vs baseline: 1.2672x; 1.0703x over previous
//
#include <hip/hip_runtime.h>
#include <math.h>

#define LSEQ 4096
#define NFFT 8192
#define NF   512     // kept frequency bins
#define NF2  1024    // 2*NF (cos/sin interleaved)
#define NH   768
#define NBH  6144    // 8*768
#define MROWS 6912   // NBH + NH (x rows + k rows share stage-A GEMM)
#define SPLIT_ROW 3584   // partial-1 row split (14*256: block-uniform at BM=256)

typedef __attribute__((ext_vector_type(8))) short short8;   // 8 bf16 (4 VGPRs)
typedef __attribute__((ext_vector_type(4))) float floatx4;  // MFMA accumulator

__device__ __forceinline__ unsigned short f2bf(float f) {
    unsigned int u = __float_as_uint(f);
    u += 0x7fff + ((u >> 16) & 1);       // round-to-nearest-even
    return (unsigned short)(u >> 16);
}

// direct HBM->LDS async copy, 16B/lane.  LDS dest = wave-uniform base + lane*16.
__device__ __forceinline__ void gld16(const unsigned short* g, const unsigned short* l) {
    __builtin_amdgcn_global_load_lds(
        (const __attribute__((address_space(1))) void*)g,
        (__attribute__((address_space(3))) void*)l, 16, 0, 0);
}

// -------- fused trig tables: T1[f2][n] and T2[n][f2], bf16 -----------------
__global__ void build_tables(unsigned short* __restrict__ T1,
                             unsigned short* __restrict__ T2) {
    __shared__ unsigned short tile[64][66];
    const int t = threadIdx.x;
    const int F0 = blockIdx.x * 64;
    const int N0 = blockIdx.y * 64;
#pragma unroll
    for (int i = 0; i < 16; ++i) {
        int r = (t >> 6) + i * 4;
        int c = t & 63;
        int f2 = F0 + r, n = N0 + c;
        int f = f2 >> 1;
        int p = (f * n) & (NFFT - 1);
        float th = (float)p * (float)(2.0 * M_PI / (double)NFFT);
        float s, cc;
        sincosf(th, &s, &cc);
        unsigned short v = f2bf((f2 & 1) ? s : cc);
        T1[(size_t)f2 * LSEQ + n] = v;
        tile[r][c] = v;
    }
    __syncthreads();
#pragma unroll
    for (int i = 0; i < 16; ++i) {
        int r = (t >> 6) + i * 4;
        int c = t & 63;
        T2[(size_t)(N0 + r) * NF2 + F0 + c] = tile[c][r];
    }
}

// -------- fp32 -> bf16 pack of [x ; k] into one [6912, 4096] matrix --------
__global__ void tobf16(const float* __restrict__ x, const float* __restrict__ kk,
                       unsigned short* __restrict__ o) {
    size_t e = ((size_t)blockIdx.x * 256 + threadIdx.x) * 4;
    const size_t XN = (size_t)NBH * LSEQ;
    const float* s = (e < XN) ? (x + e) : (kk + (e - XN));
    float4 v = *(const float4*)s;
    unsigned int lo = (unsigned int)f2bf(v.x) | ((unsigned int)f2bf(v.y) << 16);
    unsigned int hi = (unsigned int)f2bf(v.z) | ((unsigned int)f2bf(v.w) << 16);
    *(uint2*)(o + e) = make_uint2(lo, hi);
}

// ======== 256x256 1-barrier GEMM: C = A[M,K] x B^T[N,K], fp32 out ==========
// R7 post-mortem: 8-phase had 8 barriers/K-tile (skew ~1500cyc) + wrong 1-bit
// swizzle (8-way conflict, 765 cyc/K-tile).  R8:
//  (1) 3-bit XOR swizzle: slot = g ^ (row&7); ks=1 slot = s0^4 (XOR, bits
//      0-1 row-keyed, bit 2 = ks).  16-lane group -> 8 distinct slots ->
//      2-way = free (m136).  Stage side: lane l writes LDS slot l&7 at row
//      (l>>3), so its GLOBAL slot = (l&7)^((l>>3)&7) (involution, rule #21).
//  (2) ONE barrier + one free vmcnt(0) per K-tile:
//      iter kt: STG(kt+1 -> bs); RD+MM(64) from Sc; vmcnt(0); barrier.
//      Safety: end-of-kt barrier => all waves' reads of buf(kt) retired
//      (MM's lgkm waits precede it) before any STG(kt+2 -> buf(kt)); same
//      barrier publishes tile kt+1 (vmcnt(0) is free: its 8 loads flew
//      during the ~2300cyc compute > 900cyc HBM latency).
__global__ __launch_bounds__(512) void gemm8(
    const unsigned short* __restrict__ A,   // [M,ldk] bf16
    const unsigned short* __restrict__ B,   // [N,ldk] bf16 (transposed operand)
    float* __restrict__ C,                  // z==0 target [M,N] fp32
    float* __restrict__ P1a,                // z==1 target, rows < SPLIT_ROW
    float* __restrict__ P1b,                // z==1 target, rows >= SPLIT_ROW
    int gx, int gy, int N, int ldk, int Ksub)
{
    __shared__ __align__(16) unsigned short S[2 * 32768];   // 128 KiB: [buf][A|B]
    const int t = threadIdx.x;
    const int wid = t >> 6, l = t & 63;

    // chunked bijective XCD swizzle (nwg = 216 / 384, both %8==0)
    const int nwg = gridDim.x, bid = blockIdx.x;
    const int swz = (bid & 7) * (nwg >> 3) + (bid >> 3);
    const int bx = swz % gx;
    const int rem = swz / gx;
    const int by = rem % gy;
    const int bz = rem / gy;

    const int m0 = by * 256, n0 = bx * 256;
    const int wr = wid >> 2, wc = wid & 3;   // wave tile: rows wr*128, cols wc*64
    const int lq = l >> 4, lr = l & 15;
    const int kbase = bz * Ksub;
    const int NT = Ksub >> 6;                // K-tiles of 64

    // read side: element (row, k-slot g) lives at LDS slot g ^ (row&7);
    // frag rows = base + lr with base mult-of-16 -> row&7 = lr&7.
    // ks=0 k-slot = lq, ks=1 k-slot = lq+4 -> slots s0 and s0^4.
    const int s0 = lq ^ (lr & 7);
    const int aoff = (wr * 128 + lr) * 64 + s0 * 8;            // shorts
    const int boff = 16384 + (wc * 64 + lr) * 64 + s0 * 8;

    // stage side: linear LDS dest (gld16); lane l covers row wid*8+(l>>3),
    // LDS slot l&7 -> global k-slot (l&7)^((l>>3)&7) (row offsets are mult-64)
    const int gsl = (l & 7) ^ ((l >> 3) & 7);
    const unsigned short* pAs = A + (size_t)(m0 + wid * 8 + (l >> 3)) * ldk + kbase + gsl * 8;
    const unsigned short* pBs = B + (size_t)(n0 + wid * 8 + (l >> 3)) * ldk + kbase + gsl * 8;

    floatx4 acc[8][4];
#pragma unroll
    for (int i = 0; i < 8; ++i)
#pragma unroll
        for (int j = 0; j < 4; ++j)
            acc[i][j] = (floatx4){0.f, 0.f, 0.f, 0.f};

// full tile stage = 8 gld16 calls (4 A-rows-of-64, 4 B-rows-of-64)
#define STG_TILE(b, kt_)                                                                   \
    gld16(pAs + (size_t)  0 * ldk + (kt_) * 64, S + (b)*32768 +         (  0 + wid*8) * 64); \
    gld16(pAs + (size_t) 64 * ldk + (kt_) * 64, S + (b)*32768 +         ( 64 + wid*8) * 64); \
    gld16(pAs + (size_t)128 * ldk + (kt_) * 64, S + (b)*32768 +         (128 + wid*8) * 64); \
    gld16(pAs + (size_t)192 * ldk + (kt_) * 64, S + (b)*32768 +         (192 + wid*8) * 64); \
    gld16(pBs + (size_t)  0 * ldk + (kt_) * 64, S + (b)*32768 + 16384 + (  0 + wid*8) * 64); \
    gld16(pBs + (size_t) 64 * ldk + (kt_) * 64, S + (b)*32768 + 16384 + ( 64 + wid*8) * 64); \
    gld16(pBs + (size_t)128 * ldk + (kt_) * 64, S + (b)*32768 + 16384 + (128 + wid*8) * 64); \
    gld16(pBs + (size_t)192 * ldk + (kt_) * 64, S + (b)*32768 + 16384 + (192 + wid*8) * 64);

// ks=1 slot = s0^4 -> byte-offset bit5 flip: (aoff ^ 32) (row terms bits>=6)
#define RD_A(Sc, ip)                                                           \
    _Pragma("unroll") for (int ii = 0; ii < 2; ++ii)                           \
    _Pragma("unroll") for (int ks = 0; ks < 2; ++ks)                           \
        aq[ii][ks] = *(const short8*)((Sc) + ((aoff ^ (ks * 32)) + 1024 * ((ip) + ii)));
#define RD_B(Sc)                                                               \
    _Pragma("unroll") for (int j = 0; j < 4; ++j)                              \
    _Pragma("unroll") for (int ks = 0; ks < 2; ++ks)                           \
        bq[j][ks] = *(const short8*)((Sc) + ((boff ^ (ks * 32)) + 1024 * j));
#define MM(ip)                                                                 \
    __builtin_amdgcn_s_setprio(1);                                             \
    _Pragma("unroll") for (int ii = 0; ii < 2; ++ii)                           \
    _Pragma("unroll") for (int j = 0; j < 4; ++j)                              \
    _Pragma("unroll") for (int ks = 0; ks < 2; ++ks)                           \
        acc[(ip) + ii][j] = __builtin_amdgcn_mfma_f32_16x16x32_bf16(           \
            aq[ii][ks], bq[j][ks], acc[(ip) + ii][j], 0, 0, 0);                \
    __builtin_amdgcn_s_setprio(0);

    // prologue: tile 0 -> buf 0, drain (first use: no stale-read hazard)
    STG_TILE(0, 0)
    asm volatile("s_waitcnt vmcnt(0)" ::: "memory");
    __builtin_amdgcn_s_barrier();
    __builtin_amdgcn_sched_barrier(0);

    short8 aq[2][2], bq[4][2];

    for (int kt = 0; kt < NT; ++kt) {
        const unsigned short* Sc = S + (size_t)(kt & 1) * 32768;
        const int bs = (kt & 1) ^ 1;
        const bool pf = (kt + 1 < NT);
        // stage kt+1 into bs: safe -- the barrier we just passed guarantees
        // every wave finished iter kt-1 (the last reads of buf bs)
        if (pf) { STG_TILE(bs, kt + 1) }
        // compute tile kt (published by the barrier we just passed)
        RD_B(Sc)
        RD_A(Sc, 0) MM(0)
        RD_A(Sc, 2) MM(2)
        RD_A(Sc, 4) MM(4)
        RD_A(Sc, 6) MM(6)
        if (pf) {
            // free drain: tile kt+1's 8 loads flew during the compute above
            asm volatile("s_waitcnt vmcnt(0)" ::: "memory");
            __builtin_amdgcn_s_barrier();     // publish kt+1; retire kt reads
            __builtin_amdgcn_sched_barrier(0);
        }
    }

    // epilogue target: z=0 -> C; z=1 -> partial (block-uniform row split)
    float* Cb;
    if (bz == 0) Cb = C;
    else Cb = (m0 < SPLIT_ROW) ? P1a : (P1b - (size_t)SPLIT_ROW * N);
    // C/D layout: col = lane&15, row = (lane>>4)*4 + reg  [verified m89/m91]
#pragma unroll
    for (int i = 0; i < 8; ++i)
#pragma unroll
        for (int j = 0; j < 4; ++j)
#pragma unroll
            for (int r = 0; r < 4; ++r) {
                int row = m0 + wr * 128 + 16 * i + lq * 4 + r;
                int col = n0 + wc * 64 + 16 * j + lr;
                Cb[(size_t)row * N + col] = acc[i][j][r];
            }
}

// -------- combine: sum K-split partials + complex multiply + scaling -------
__global__ void combine(const float* __restrict__ C1,
                        const float* __restrict__ P1a,
                        const float* __restrict__ P1b,
                        unsigned short* __restrict__ AB) {
    int idx = blockIdx.x * blockDim.x + threadIdx.x;   // bh*512 + f
    int bh = idx >> 9;
    int f = idx & (NF - 1);
    int h = bh % NH;
    const float* xc = C1 + (size_t)bh * NF2 + 2 * f;
    const float* xp = (bh < SPLIT_ROW)
        ? (P1a + (size_t)bh * NF2 + 2 * f)
        : (P1b + (size_t)(bh - SPLIT_ROW) * NF2 + 2 * f);
    const int kr = NBH + h;    // always >= SPLIT_ROW
    const float* kc = C1 + (size_t)kr * NF2 + 2 * f;
    const float* kp = P1b + (size_t)(kr - SPLIT_ROW) * NF2 + 2 * f;
    float Xre = xc[0] + xp[0], Xim = -(xc[1] + xp[1]);
    float Kre = kc[0] + kp[0], Kim = -(kc[1] + kp[1]);
    float s = (f == 0 ? 1.0f : 2.0f) * (1.0f / (float)NFFT);
    float Av = s * (Xre * Kre - Xim * Kim);
    float Bv = -(s * (Xre * Kim + Xim * Kre));
    unsigned int packed = (unsigned int)f2bf(Av) | ((unsigned int)f2bf(Bv) << 16);
    *(unsigned int*)(AB + (size_t)bh * NF2 + 2 * f) = packed;
}

extern "C" void kernel_launch(void* const* d_in, const int* in_sizes, int n_in,
                              void* d_out, int out_size, void* d_ws, size_t ws_size,
                              hipStream_t stream) {
    const float* x = (const float*)d_in[0];   // [8,768,4096]
    const float* k = (const float*)d_in[1];   // [768,4096]
    float* y = (float*)d_out;

    // ws layout (44.0 MB of 45.1 MB proven):
    unsigned short* T1 = (unsigned short*)d_ws;                 // [1024,4096] bf16,  8.39 MB
    unsigned short* T2 = T1 + (size_t)NF2 * LSEQ;               // [4096,1024] bf16,  8.39 MB
    unsigned short* AB = T2 + (size_t)LSEQ * NF2;               // [6144,1024] bf16, 12.58 MB
    float* P1a = (float*)(AB + (size_t)NBH * NF2);              // [3584,1024] f32,  14.68 MB

    // d_out as scratch (98.6 MB of 100.66) until stage B overwrites:
    unsigned short* Abm = (unsigned short*)d_out;               // [6912,4096] bf16, 56.62 MB
    float* C1 = (float*)((char*)d_out + (size_t)MROWS * LSEQ * 2); // [6912,1024] f32, 28.31 MB
    float* P1b = C1 + (size_t)MROWS * NF2;                      // [3328,1024] f32,  13.63 MB

    const int blk = 256;
    hipLaunchKernelGGL(build_tables, dim3(NF2 / 64, LSEQ / 64), dim3(blk), 0, stream, T1, T2);
    hipLaunchKernelGGL(tobf16, dim3((MROWS * LSEQ / 4) / blk), dim3(blk), 0, stream, x, k, Abm);
    // Stage A: [6912,4096] x [4096,1024], 256^2 tiles, split-K x2: 4*27*2=216 WGs
    hipLaunchKernelGGL(gemm8, dim3(4 * 27 * 2), dim3(512), 0, stream,
                       Abm, T1, C1, P1a, P1b, 4, 27, NF2, LSEQ, LSEQ / 2);
    hipLaunchKernelGGL(combine, dim3((NBH * NF) / blk), dim3(blk), 0, stream, C1, P1a, P1b, AB);
    // Stage B: [6144,1024] x [1024,4096] -> y: 16*24=384 WGs
    hipLaunchKernelGGL(gemm8, dim3(16 * 24), dim3(512), 0, stream,
                       AB, T2, y, (float*)nullptr, (float*)nullptr, 16, 24, LSEQ, NF2, NF2);
}